// Round 3
// baseline (14849.628 us; speedup 1.0000x reference)
//
#include <hip/hip_runtime.h>
#include <cstdint>

#define NN 25000
#define NE 300000
#define NB 25
#define NCH 32
#define CH (NE / NCH)   // 9375 edges per chunk

__device__ __forceinline__ float4 ld4(const float* p){ return *reinterpret_cast<const float4*>(p); }
__device__ __forceinline__ void st4(float* p, const float4& v){ *reinterpret_cast<float4*>(p) = v; }

// fixed-point helpers: deterministic (order-independent) segment sums.
// scale 2^32; |contrib| <= ~250 -> needs <=42 bits -> double conversion exact.
#define FXS 4294967296.0
#define FXI 2.3283064365386963e-10
__device__ __forceinline__ void atomAddFx(long long* p, float v) {
  long long q = (long long)llrint((double)v * FXS);
  atomicAdd((unsigned long long*)p, (unsigned long long)q);
}
__device__ __forceinline__ float fx2f(long long q) {
  return (float)((double)q * FXI);
}

// ---------------- gather rows of a [*,128] table ----------------
__global__ __launch_bounds__(256)
void gather_k(const float* __restrict__ tab, const int* __restrict__ idx,
              float* __restrict__ out, int M)
{
  int t = blockIdx.x * 256 + threadIdx.x;
  if (t >= M * 32) return;
  int i = t >> 5, c4 = t & 31;
  st4(out + (size_t)i * 128 + c4 * 4, ld4(tab + (size_t)idx[i] * 128 + c4 * 4));
}

// ---------------- generic [M,128]@[128,128] GEMM, optional bias+resid+LN ----
// 256 threads, 32 rows/block. W staged in LDS (64KB), X tile 16KB. 80KB LDS.
__global__ __launch_bounds__(256)
void gemm128_k(const float* __restrict__ X, const float* __restrict__ W,
               const float* __restrict__ Bias, const float* __restrict__ Resid,
               const float* __restrict__ G, const float* __restrict__ Bb,
               float* __restrict__ OUT, int M)
{
  __shared__ float Ws[128 * 128];   // reused as T[32][132] in LN epilogue
  __shared__ float Xs[32 * 128];    // head 64 floats reused as mu/rsd after k-loop
  const int tid = threadIdx.x;
  const int m0 = blockIdx.x * 32;

  for (int idx = tid; idx < 32 * 32; idx += 256) {
    int r = idx >> 5, c4 = idx & 31;
    float4 v = make_float4(0.f, 0.f, 0.f, 0.f);
    if (m0 + r < M) v = ld4(X + (size_t)(m0 + r) * 128 + c4 * 4);
    st4(Xs + r * 128 + c4 * 4, v);
  }
  for (int idx = tid; idx < 4096; idx += 256)
    st4(Ws + idx * 4, ld4(W + idx * 4));
  __syncthreads();

  const int tr = tid >> 5, tc = tid & 31;   // 8 row-groups x 32 col-groups
  float acc[4][4] = {};
  for (int k0 = 0; k0 < 128; k0 += 4) {
    float xr[4][4], wr[4][4];
#pragma unroll
    for (int i = 0; i < 4; i++) {
      float4 t = ld4(Xs + (tr * 4 + i) * 128 + k0);
      xr[i][0] = t.x; xr[i][1] = t.y; xr[i][2] = t.z; xr[i][3] = t.w;
    }
#pragma unroll
    for (int kk = 0; kk < 4; kk++) {
      float4 t = ld4(Ws + (k0 + kk) * 128 + tc * 4);
      wr[kk][0] = t.x; wr[kk][1] = t.y; wr[kk][2] = t.z; wr[kk][3] = t.w;
    }
#pragma unroll
    for (int kk = 0; kk < 4; kk++)
#pragma unroll
      for (int i = 0; i < 4; i++)
#pragma unroll
        for (int j = 0; j < 4; j++)
          acc[i][j] = fmaf(xr[i][kk], wr[kk][j], acc[i][j]);
  }

  if (G == nullptr) {   // plain GEMM (QKV / pe): no bias in reference
#pragma unroll
    for (int i = 0; i < 4; i++) {
      int row = m0 + tr * 4 + i;
      if (row < M)
        st4(OUT + (size_t)row * 128 + tc * 4,
            make_float4(acc[i][0], acc[i][1], acc[i][2], acc[i][3]));
    }
    return;
  }

  // epilogue: t = acc + bias + resid ; LN(t) with scale G, bias Bb
  __syncthreads();                  // everyone done reading Ws/Xs
  float* T = Ws;                    // [32][132] padded
  float* mu = Xs; float* rsd = Xs + 32;
  float4 bv = ld4(Bias + tc * 4);
#pragma unroll
  for (int i = 0; i < 4; i++) {
    int r = tr * 4 + i;
    float4 rv = make_float4(0.f, 0.f, 0.f, 0.f);
    if (m0 + r < M) rv = ld4(Resid + (size_t)(m0 + r) * 128 + tc * 4);
    st4(T + r * 132 + tc * 4,
        make_float4(acc[i][0] + bv.x + rv.x, acc[i][1] + bv.y + rv.y,
                    acc[i][2] + bv.z + rv.z, acc[i][3] + bv.w + rv.w));
  }
  __syncthreads();
  {
    int r = tid >> 3, jj = tid & 7;   // 32 rows x 8 threads
    const float* tp = T + r * 132;
    float s = 0.f;
    for (int c = jj * 16; c < jj * 16 + 16; c++) s += tp[c];
    s += __shfl_xor(s, 1); s += __shfl_xor(s, 2); s += __shfl_xor(s, 4);
    float mean = s * (1.f / 128.f);
    float v = 0.f;
    for (int c = jj * 16; c < jj * 16 + 16; c++) { float d = tp[c] - mean; v += d * d; }
    v += __shfl_xor(v, 1); v += __shfl_xor(v, 2); v += __shfl_xor(v, 4);
    if (jj == 0) { mu[r] = mean; rsd[r] = 1.0f / sqrtf(v * (1.f / 128.f) + 1e-5f); }
  }
  __syncthreads();
  float4 gv = ld4(G + tc * 4), bbv = ld4(Bb + tc * 4);
#pragma unroll
  for (int i = 0; i < 4; i++) {
    int r = tr * 4 + i, row = m0 + r;
    if (row < M) {
      float4 t = ld4(T + r * 132 + tc * 4);
      float m = mu[r], rr = rsd[r];
      st4(OUT + (size_t)row * 128 + tc * 4,
          make_float4(gv.x * (t.x - m) * rr + bbv.x, gv.y * (t.y - m) * rr + bbv.y,
                      gv.z * (t.z - m) * rr + bbv.z, gv.w * (t.w - m) * rr + bbv.w));
    }
  }
}

// ---------------- fused FFN: out = LN(x + relu(x@W1+b1)@W2+b2) ----------------
// 16 rows/block. Weights staged in 64KB halves -> ~89KB LDS total.
__global__ __launch_bounds__(256)
void ffn_k(const float* __restrict__ X, float* __restrict__ OUT,
           const float* __restrict__ W1, const float* __restrict__ B1,
           const float* __restrict__ W2, const float* __restrict__ B2,
           const float* __restrict__ G, const float* __restrict__ Bb, int M)
{
  __shared__ float Wb[128 * 128];   // one 64KB weight half at a time
  __shared__ float Xs[16 * 128];
  __shared__ float Mid[16 * 264];   // [16][256] +8 pad; reused as T[16][132]
  __shared__ float mu[16], rsd[16];
  const int tid = threadIdx.x;
  const int m0 = blockIdx.x * 16;
  const int tr = tid >> 5;          // 0..7 -> rows tr*2, tr*2+1
  const int tc = tid & 31;          // col4 group

  for (int idx = tid; idx < 16 * 32; idx += 256) {
    int r = idx >> 5, c4 = idx & 31;
    float4 v = make_float4(0.f, 0.f, 0.f, 0.f);
    if (m0 + r < M) v = ld4(X + (size_t)(m0 + r) * 128 + c4 * 4);
    st4(Xs + r * 128 + c4 * 4, v);
  }

  // pass 1: Mid = relu(Xs@W1 + b1), in two 128-col halves
  for (int half = 0; half < 2; ++half) {
    __syncthreads();   // Xs ready (h=0) / prior Wb readers done (h=1)
    for (int idx = tid; idx < 4096; idx += 256) {
      int r = idx >> 5, c4 = idx & 31;
      st4(Wb + r * 128 + c4 * 4, ld4(W1 + (size_t)r * 256 + half * 128 + c4 * 4));
    }
    __syncthreads();
    float a[2][4] = {};
    for (int k0 = 0; k0 < 128; k0 += 4) {
      float xr[2][4], wr[4][4];
#pragma unroll
      for (int i = 0; i < 2; i++) {
        float4 t = ld4(Xs + (tr * 2 + i) * 128 + k0);
        xr[i][0] = t.x; xr[i][1] = t.y; xr[i][2] = t.z; xr[i][3] = t.w;
      }
#pragma unroll
      for (int kk = 0; kk < 4; kk++) {
        float4 t = ld4(Wb + (k0 + kk) * 128 + tc * 4);
        wr[kk][0] = t.x; wr[kk][1] = t.y; wr[kk][2] = t.z; wr[kk][3] = t.w;
      }
#pragma unroll
      for (int kk = 0; kk < 4; kk++)
#pragma unroll
        for (int i = 0; i < 2; i++)
#pragma unroll
          for (int j = 0; j < 4; j++)
            a[i][j] = fmaf(xr[i][kk], wr[kk][j], a[i][j]);
    }
    float4 b1v = ld4(B1 + half * 128 + tc * 4);
    float bb[4] = { b1v.x, b1v.y, b1v.z, b1v.w };
#pragma unroll
    for (int i = 0; i < 2; i++)
#pragma unroll
      for (int j = 0; j < 4; j++)
        Mid[(tr * 2 + i) * 264 + half * 128 + tc * 4 + j] = fmaxf(a[i][j] + bb[j], 0.f);
  }

  // pass 2: acc2 = Mid@W2, in two 128-k halves
  float acc2[2][4] = {};
  for (int half = 0; half < 2; ++half) {
    __syncthreads();   // Mid writes done (h=0) / Wb readers done (h=1)
    for (int idx = tid; idx < 4096; idx += 256) {
      int r = idx >> 5, c4 = idx & 31;
      st4(Wb + r * 128 + c4 * 4, ld4(W2 + (size_t)(half * 128 + r) * 128 + c4 * 4));
    }
    __syncthreads();
    for (int k0 = 0; k0 < 128; k0 += 4) {
      float xr[2][4], wr[4][4];
#pragma unroll
      for (int i = 0; i < 2; i++) {
        float4 t = ld4(Mid + (tr * 2 + i) * 264 + half * 128 + k0);
        xr[i][0] = t.x; xr[i][1] = t.y; xr[i][2] = t.z; xr[i][3] = t.w;
      }
#pragma unroll
      for (int kk = 0; kk < 4; kk++) {
        float4 t = ld4(Wb + (k0 + kk) * 128 + tc * 4);
        wr[kk][0] = t.x; wr[kk][1] = t.y; wr[kk][2] = t.z; wr[kk][3] = t.w;
      }
#pragma unroll
      for (int kk = 0; kk < 4; kk++)
#pragma unroll
        for (int i = 0; i < 2; i++)
#pragma unroll
          for (int j = 0; j < 4; j++)
            acc2[i][j] = fmaf(xr[i][kk], wr[kk][j], acc2[i][j]);
    }
  }

  // epilogue: T = acc2 + b2 + resid(Xs); LN
  float4 b2v = ld4(B2 + tc * 4);
  __syncthreads();                 // all reads of Mid done before overwrite
  float* T = Mid;                  // [16][132]
#pragma unroll
  for (int i = 0; i < 2; i++) {
    int r = tr * 2 + i;
    float4 xv = ld4(Xs + r * 128 + tc * 4);
    st4(T + r * 132 + tc * 4,
        make_float4(acc2[i][0] + b2v.x + xv.x, acc2[i][1] + b2v.y + xv.y,
                    acc2[i][2] + b2v.z + xv.z, acc2[i][3] + b2v.w + xv.w));
  }
  __syncthreads();
  {
    int r = tid >> 4, jj = tid & 15;   // 16 rows x 16 threads
    const float* tp = T + r * 132;
    float s = 0.f;
    for (int c = jj * 8; c < jj * 8 + 8; c++) s += tp[c];
    s += __shfl_xor(s, 1); s += __shfl_xor(s, 2); s += __shfl_xor(s, 4); s += __shfl_xor(s, 8);
    float mean = s * (1.f / 128.f);
    float v = 0.f;
    for (int c = jj * 8; c < jj * 8 + 8; c++) { float d = tp[c] - mean; v += d * d; }
    v += __shfl_xor(v, 1); v += __shfl_xor(v, 2); v += __shfl_xor(v, 4); v += __shfl_xor(v, 8);
    if (jj == 0) { mu[r] = mean; rsd[r] = 1.0f / sqrtf(v * (1.f / 128.f) + 1e-5f); }
  }
  __syncthreads();
  for (int idx = tid; idx < 16 * 32; idx += 256) {
    int r = idx >> 5, c4 = idx & 31;
    int row = m0 + r;
    if (row < M) {
      float4 t = ld4(T + r * 132 + c4 * 4);
      float4 gv = ld4(G + c4 * 4), bbv = ld4(Bb + c4 * 4);
      float m = mu[r], rr = rsd[r];
      st4(OUT + (size_t)row * 128 + c4 * 4,
          make_float4(gv.x * (t.x - m) * rr + bbv.x, gv.y * (t.y - m) * rr + bbv.y,
                      gv.z * (t.z - m) * rr + bbv.z, gv.w * (t.w - m) * rr + bbv.w));
    }
  }
}

// ---------------- per-edge attention: score + deterministic fixed-point sums --
__global__ __launch_bounds__(256)
void edge_k(const float* __restrict__ Q, const float* __restrict__ K,
            const float* __restrict__ V, float* __restrict__ PE,  // in: pe, out: score
            const int* __restrict__ src, const int* __restrict__ dst,
            long long* __restrict__ wV, long long* __restrict__ z, int E)
{
  int e = blockIdx.x * 8 + (threadIdx.x >> 5);
  if (e >= E) return;
  int j = threadIdx.x & 31;
  int s = src[e], d = dst[e];
  float4 kv = ld4(K + (size_t)s * 128 + j * 4);
  float4 qv = ld4(Q + (size_t)d * 128 + j * 4);
  float4 pv = ld4(PE + (size_t)e * 128 + j * 4);
  float4 sc = make_float4(kv.x * qv.x * 0.25f * pv.x, kv.y * qv.y * 0.25f * pv.y,
                          kv.z * qv.z * 0.25f * pv.z, kv.w * qv.w * 0.25f * pv.w);
  st4(PE + (size_t)e * 128 + j * 4, sc);     // e_att written in place of pe
  float ssum = sc.x + sc.y + sc.z + sc.w;
  ssum += __shfl_xor(ssum, 1);
  ssum += __shfl_xor(ssum, 2);               // per-head (16-ch) sum across 4 lanes
  float w = expf(fminf(fmaxf(ssum, -5.f), 5.f));
  float4 vv = ld4(V + (size_t)s * 128 + j * 4);
  long long* wvp = wV + (size_t)d * 128 + j * 4;
  atomAddFx(wvp + 0, vv.x * w);
  atomAddFx(wvp + 1, vv.y * w);
  atomAddFx(wvp + 2, vv.z * w);
  atomAddFx(wvp + 3, vv.w * w);
  if ((j & 3) == 0) atomAddFx(&z[(size_t)d * 8 + (j >> 2)], w);
}

// ---------------- h_att = wV / (z + 1e-6)  (fixed-point -> float) ------------
__global__ __launch_bounds__(256)
void hatt_k(const long long* __restrict__ wV, const long long* __restrict__ z,
            float* __restrict__ OUT)
{
  int t = blockIdx.x * 256 + threadIdx.x;
  int n = t >> 5, c4 = t & 31;
  float zz = fx2f(z[(size_t)n * 8 + (c4 >> 2)]) + 1e-6f;
  const long long* wp = wV + (size_t)n * 128 + c4 * 4;
  float4 v = make_float4(fx2f(wp[0]), fx2f(wp[1]), fx2f(wp[2]), fx2f(wp[3]));
  v.x /= zz; v.y /= zz; v.z /= zz; v.w /= zz;
  st4(OUT + (size_t)n * 128 + c4 * 4, v);
}

// ---------------- per-graph mean over 1000 nodes ----------------
__global__ __launch_bounds__(256)
void graphmean_k(const float* __restrict__ h, float* __restrict__ hg)
{
  __shared__ float red[256];
  int g = blockIdx.x, tid = threadIdx.x;
  int c = tid & 127, half = tid >> 7;
  float s = 0.f;
  for (int r = half; r < 1000; r += 2) s += h[(size_t)(g * 1000 + r) * 128 + c];
  red[tid] = s;
  __syncthreads();
  if (half == 0) hg[g * 128 + c] = (red[c] + red[c + 128]) / 1000.0f;
}

// ---------------- readout MLP: 128 -> 64 -> 32 -> 1 ----------------
__global__ __launch_bounds__(256)
void readout_k(const float* __restrict__ hg,
               const float* __restrict__ w0, const float* __restrict__ b0,
               const float* __restrict__ w1, const float* __restrict__ b1,
               const float* __restrict__ w2, const float* __restrict__ b2,
               float* __restrict__ out)
{
  __shared__ float hs[25 * 128];
  __shared__ float t0[25 * 64];
  __shared__ float t1[25 * 32];
  int tid = threadIdx.x;
  for (int i = tid; i < 25 * 128; i += 256) hs[i] = hg[i];
  __syncthreads();
  for (int i = tid; i < 25 * 64; i += 256) {
    int r = i >> 6, c = i & 63;
    float a = b0[c];
    for (int k = 0; k < 128; k++) a += hs[r * 128 + k] * w0[k * 64 + c];
    t0[i] = fmaxf(a, 0.f);
  }
  __syncthreads();
  for (int i = tid; i < 25 * 32; i += 256) {
    int r = i >> 5, c = i & 31;
    float a = b1[c];
    for (int k = 0; k < 64; k++) a += t0[r * 64 + k] * w1[k * 32 + c];
    t1[i] = fmaxf(a, 0.f);
  }
  __syncthreads();
  if (tid < 25) {
    float a = b2[0];
    for (int k = 0; k < 32; k++) a += t1[tid * 32 + k] * w2[k];
    out[tid] = a;
  }
}

extern "C" void kernel_launch(void* const* d_in, const int* in_sizes, int n_in,
                              void* d_out, int out_size, void* d_ws, size_t ws_size,
                              hipStream_t stream)
{
  const float* emb_h  = (const float*)d_in[0];
  const float* emb_e  = (const float*)d_in[1];
  const float* w_qkve = (const float*)d_in[2];
  const float* o_w    = (const float*)d_in[3];
  const float* o_b    = (const float*)d_in[4];
  const float* ln_s   = (const float*)d_in[5];
  const float* ln_b   = (const float*)d_in[6];
  const float* ffn_w1 = (const float*)d_in[7];
  const float* ffn_b1 = (const float*)d_in[8];
  const float* ffn_w2 = (const float*)d_in[9];
  const float* ffn_b2 = (const float*)d_in[10];
  const float* mlp_w0 = (const float*)d_in[11];
  const float* mlp_b0 = (const float*)d_in[12];
  const float* mlp_w1 = (const float*)d_in[13];
  const float* mlp_b1 = (const float*)d_in[14];
  const float* mlp_w2 = (const float*)d_in[15];
  const float* mlp_b2 = (const float*)d_in[16];
  const int* tokens = (const int*)d_in[17];
  const int* etype  = (const int*)d_in[18];
  const int* src    = (const int*)d_in[19];
  const int* dst    = (const int*)d_in[20];
  // d_in[21] graph_id: implied by node index / 1000

  // workspace budget (bytes):
  //   wV_ll 25.6M + z_ll 1.6M + h/Q/K/V 51.2M + hg 12.8K + e 153.6M + pe 4.8M
  //   = 236.8 MB  (<= 237.6 MB that ran in round 2)
  // 8-byte buffers first for alignment.
  char* ws = (char*)d_ws;
  size_t off = 0;
  auto alloc = [&](size_t bytes) { char* p = ws + off; off += bytes; return p; };
  long long* wVll = (long long*)alloc((size_t)NN * 128 * 8);
  long long* zll  = (long long*)alloc((size_t)NN * 8 * 8);
  float* h  = (float*)alloc((size_t)NN * 128 * 4);
  float* Qb = (float*)alloc((size_t)NN * 128 * 4);
  float* Kb = (float*)alloc((size_t)NN * 128 * 4);
  float* Vb = (float*)alloc((size_t)NN * 128 * 4);
  float* hg = (float*)alloc(25 * 128 * 4);
  float* e  = (float*)alloc((size_t)NE * 128 * 4);
  float* pe = (float*)alloc((size_t)CH * 128 * 4);  // one chunk; reused as score

  const int GB_N = (NN + 31) / 32;
  const int GB_C = (CH + 31) / 32;
  const int EB_C = (CH + 7) / 8;
  const int FB_N = (NN + 15) / 16;
  const int FB_E = NE / 16;

  gather_k<<<(NN * 32 + 255) / 256, 256, 0, stream>>>(emb_h, tokens, h, NN);
  gather_k<<<(NE * 32 + 255) / 256, 256, 0, stream>>>(emb_e, etype, e, NE);

  const size_t DD = 128 * 128;
  for (int l = 0; l < 4; ++l) {
    const float* wq  = w_qkve + ((size_t)l * 4 + 0) * DD;
    const float* wk  = w_qkve + ((size_t)l * 4 + 1) * DD;
    const float* wv  = w_qkve + ((size_t)l * 4 + 2) * DD;
    const float* we  = w_qkve + ((size_t)l * 4 + 3) * DD;
    const float* ow0 = o_w + ((size_t)l * 2 + 0) * DD;
    const float* ow1 = o_w + ((size_t)l * 2 + 1) * DD;
    const float* ob0 = o_b + ((size_t)l * 2 + 0) * 128;
    const float* ob1 = o_b + ((size_t)l * 2 + 1) * 128;
    const float* ls0 = ln_s + ((size_t)l * 4 + 0) * 128;
    const float* ls1 = ln_s + ((size_t)l * 4 + 1) * 128;
    const float* ls2 = ln_s + ((size_t)l * 4 + 2) * 128;
    const float* ls3 = ln_s + ((size_t)l * 4 + 3) * 128;
    const float* lb0 = ln_b + ((size_t)l * 4 + 0) * 128;
    const float* lb1 = ln_b + ((size_t)l * 4 + 1) * 128;
    const float* lb2 = ln_b + ((size_t)l * 4 + 2) * 128;
    const float* lb3 = ln_b + ((size_t)l * 4 + 3) * 128;
    const float* f1h = ffn_w1 + ((size_t)l * 2 + 0) * 128 * 256;
    const float* f1e = ffn_w1 + ((size_t)l * 2 + 1) * 128 * 256;
    const float* fb1h = ffn_b1 + ((size_t)l * 2 + 0) * 256;
    const float* fb1e = ffn_b1 + ((size_t)l * 2 + 1) * 256;
    const float* f2h = ffn_w2 + ((size_t)l * 2 + 0) * 256 * 128;
    const float* f2e = ffn_w2 + ((size_t)l * 2 + 1) * 256 * 128;
    const float* fb2h = ffn_b2 + ((size_t)l * 2 + 0) * 128;
    const float* fb2e = ffn_b2 + ((size_t)l * 2 + 1) * 128;

    gemm128_k<<<GB_N, 256, 0, stream>>>(h, wq, nullptr, nullptr, nullptr, nullptr, Qb, NN);
    gemm128_k<<<GB_N, 256, 0, stream>>>(h, wk, nullptr, nullptr, nullptr, nullptr, Kb, NN);
    gemm128_k<<<GB_N, 256, 0, stream>>>(h, wv, nullptr, nullptr, nullptr, nullptr, Vb, NN);

    hipMemsetAsync(wVll, 0, (size_t)NN * 128 * 8, stream);
    hipMemsetAsync(zll, 0, (size_t)NN * 8 * 8, stream);

    // edge pipeline in chunks; pe buffer reused per chunk.
    for (int c = 0; c < NCH; ++c) {
      const size_t eo = (size_t)c * CH;
      gemm128_k<<<GB_C, 256, 0, stream>>>(e + eo * 128, we, nullptr, nullptr, nullptr,
                                          nullptr, pe, CH);
      edge_k<<<EB_C, 256, 0, stream>>>(Qb, Kb, Vb, pe, src + eo, dst + eo, wVll, zll, CH);
      gemm128_k<<<GB_C, 256, 0, stream>>>(pe, ow1, ob1, e + eo * 128, ls1, lb1,
                                          e + eo * 128, CH);
    }

    // h_att -> Qb (Q dead after edge chunks)
    hatt_k<<<(NN * 32) / 256, 256, 0, stream>>>(wVll, zll, Qb);

    // h = LN(h + h_att@O_h + b)   (in place)
    gemm128_k<<<GB_N, 256, 0, stream>>>(Qb, ow0, ob0, h, ls0, lb0, h, NN);

    ffn_k<<<FB_N, 256, 0, stream>>>(h, h, f1h, fb1h, f2h, fb2h, ls2, lb2, NN);
    ffn_k<<<FB_E, 256, 0, stream>>>(e, e, f1e, fb1e, f2e, fb2e, ls3, lb3, NE);
  }

  graphmean_k<<<25, 256, 0, stream>>>(h, hg);
  readout_k<<<1, 256, 0, stream>>>(hg, mlp_w0, mlp_b0, mlp_w1, mlp_b1, mlp_w2, mlp_b2,
                                   (float*)d_out);
}

// Round 4
// 9721.172 us; speedup vs baseline: 1.5276x; 1.5276x over previous
//
#include <hip/hip_runtime.h>
#include <cstdint>

#define NN 25000
#define NE 300000

typedef unsigned short ushort_t;
typedef __attribute__((ext_vector_type(8))) short bf16x8;
typedef __attribute__((ext_vector_type(4))) float f32x4;
typedef __attribute__((ext_vector_type(4))) unsigned short u16x4;
typedef __attribute__((ext_vector_type(8))) unsigned short u16x8;

__device__ __forceinline__ float4 ld4(const float* p){ return *reinterpret_cast<const float4*>(p); }
__device__ __forceinline__ void st4(float* p, const float4& v){ *reinterpret_cast<float4*>(p) = v; }
__device__ __forceinline__ float bf2f(ushort_t u){ return __uint_as_float((unsigned)u << 16); }
__device__ __forceinline__ ushort_t f2bfu(float f){
  unsigned x = __float_as_uint(f);
  return (ushort_t)((x + 0x7fffu + ((x >> 16) & 1u)) >> 16);   // RNE
}

// fixed-point (2^32) deterministic segment sums (order-independent int adds)
#define FXS 4294967296.0
#define FXI 2.3283064365386963e-10
__device__ __forceinline__ void atomAddFx(long long* p, float v) {
  long long q = (long long)llrint((double)v * FXS);
  atomicAdd((unsigned long long*)p, (unsigned long long)q);
}
__device__ __forceinline__ float fx2f(long long q) { return (float)((double)q * FXI); }

// ---------- weight convert+transpose: dst[mat][n][k] = bf16(src[mat][k][n]) ----------
__global__ __launch_bounds__(256)
void wconv_k(const float* __restrict__ src, ushort_t* __restrict__ dst,
             int K, int N, int total)
{
  int i = blockIdx.x * 256 + threadIdx.x;
  if (i >= total) return;
  int kn = K * N;
  int mat = i / kn, r = i - mat * kn;
  int n = r / K, k = r - n * K;
  dst[i] = f2bfu(src[(size_t)mat * kn + (size_t)k * N + n]);
}

// ---------- gathers ----------
__global__ __launch_bounds__(256)
void gather_h_k(const float* __restrict__ tab, const int* __restrict__ idx,
                float* __restrict__ hf, ushort_t* __restrict__ hb)
{
  int t = blockIdx.x * 256 + threadIdx.x;
  if (t >= NN * 32) return;
  int i = t >> 5, c4 = t & 31;
  float4 v = ld4(tab + (size_t)idx[i] * 128 + c4 * 4);
  st4(hf + (size_t)i * 128 + c4 * 4, v);
  u16x4 b = { f2bfu(v.x), f2bfu(v.y), f2bfu(v.z), f2bfu(v.w) };
  *reinterpret_cast<u16x4*>(hb + (size_t)i * 128 + c4 * 4) = b;
}

__global__ __launch_bounds__(256)
void gather_e_k(const float* __restrict__ tab, const int* __restrict__ idx,
                ushort_t* __restrict__ eb)
{
  int t = blockIdx.x * 256 + threadIdx.x;
  if (t >= NE * 32) return;
  int i = t >> 5, c4 = t & 31;
  float4 v = ld4(tab + (size_t)idx[i] * 128 + c4 * 4);
  u16x4 b = { f2bfu(v.x), f2bfu(v.y), f2bfu(v.z), f2bfu(v.w) };
  *reinterpret_cast<u16x4*>(eb + (size_t)i * 128 + c4 * 4) = b;
}

// ---------- MFMA GEMM: [M,128]@[128,128]; optional bias+resid+LN epilogue ----------
// 256 thr = 4 waves; tile 128x128; wave (w&1)->rows 64, (w>>1)->cols 64; 4x4 MFMA tiles.
// A-frag: lane l holds X[m, kt*32+(l>>4)*8 + j], m = base+(l&15)  (row-major LDS, pad 8)
// B-frag: lane l holds W[kt*32+(l>>4)*8+j, n], n = base+(l&15)     (WT[n][k] LDS, pad 8)
// D: col = l&15, row = (l>>4)*4 + reg   (m89-verified)
__global__ __launch_bounds__(256)
void gemm_bf_k(const ushort_t* __restrict__ Abf, const ushort_t* __restrict__ WT,
               const float* __restrict__ Bias,
               const float* __restrict__ ResF, const ushort_t* __restrict__ ResB,
               const float* __restrict__ G, const float* __restrict__ Bb,
               ushort_t* __restrict__ OutB, float* __restrict__ OutF, int M)
{
  __shared__ __align__(16) ushort_t SM[2 * 128 * 136];
  __shared__ float mu[128], rs[128];
  ushort_t* Xs = SM;
  ushort_t* Ws = SM + 128 * 136;
  const int tid = threadIdx.x;
  const int m0 = blockIdx.x * 128;

  for (int c = tid; c < 2048; c += 256) {
    int r = c >> 4, k8 = c & 15;
    bf16x8 v = {};
    if (m0 + r < M)
      v = *reinterpret_cast<const bf16x8*>(Abf + (size_t)(m0 + r) * 128 + k8 * 8);
    *reinterpret_cast<bf16x8*>(Xs + r * 136 + k8 * 8) = v;
  }
  for (int c = tid; c < 2048; c += 256)
    *reinterpret_cast<bf16x8*>(Ws + (c >> 4) * 136 + (c & 15) * 8) =
        *reinterpret_cast<const bf16x8*>(WT + (size_t)c * 8);
  __syncthreads();

  const int l = tid & 63, wv = tid >> 6;
  const int lr = l & 15, lk = l >> 4;
  const int mb = (wv & 1) * 64, nb = (wv >> 1) * 64;
  f32x4 acc[4][4];
  const f32x4 zf = {0.f, 0.f, 0.f, 0.f};
#pragma unroll
  for (int mi = 0; mi < 4; ++mi)
#pragma unroll
    for (int ni = 0; ni < 4; ++ni) acc[mi][ni] = zf;

#pragma unroll
  for (int kt = 0; kt < 4; ++kt) {
    bf16x8 af[4], bw[4];
#pragma unroll
    for (int i = 0; i < 4; ++i)
      af[i] = *reinterpret_cast<const bf16x8*>(Xs + (mb + i * 16 + lr) * 136 + kt * 32 + lk * 8);
#pragma unroll
    for (int i = 0; i < 4; ++i)
      bw[i] = *reinterpret_cast<const bf16x8*>(Ws + (nb + i * 16 + lr) * 136 + kt * 32 + lk * 8);
#pragma unroll
    for (int mi = 0; mi < 4; ++mi)
#pragma unroll
      for (int ni = 0; ni < 4; ++ni)
        acc[mi][ni] = __builtin_amdgcn_mfma_f32_16x16x32_bf16(af[mi], bw[ni], acc[mi][ni], 0, 0, 0);
  }

  if (G == nullptr) {   // plain GEMM -> bf16 out
#pragma unroll
    for (int mi = 0; mi < 4; ++mi)
#pragma unroll
      for (int rr = 0; rr < 4; ++rr) {
        int row = m0 + mb + mi * 16 + lk * 4 + rr;
        if (row < M) {
#pragma unroll
          for (int ni = 0; ni < 4; ++ni)
            OutB[(size_t)row * 128 + nb + ni * 16 + lr] = f2bfu(acc[mi][ni][rr]);
        }
      }
    return;
  }

  // epilogue: T = acc + bias + resid; LN
  __syncthreads();
  float* Tf = reinterpret_cast<float*>(SM);   // [128][132]
#pragma unroll
  for (int mi = 0; mi < 4; ++mi)
#pragma unroll
    for (int rr = 0; rr < 4; ++rr) {
      int row = mb + mi * 16 + lk * 4 + rr;
      int grow = m0 + row;
#pragma unroll
      for (int ni = 0; ni < 4; ++ni) {
        int col = nb + ni * 16 + lr;
        float t = acc[mi][ni][rr] + Bias[col];
        if (grow < M)
          t += ResF ? ResF[(size_t)grow * 128 + col] : bf2f(ResB[(size_t)grow * 128 + col]);
        Tf[row * 132 + col] = t;
      }
    }
  __syncthreads();
  {
    int r = tid >> 1, jj = tid & 1;
    const float* tp = Tf + r * 132 + jj * 64;
    float s = 0.f;
    for (int c2 = 0; c2 < 64; ++c2) s += tp[c2];
    s += __shfl_xor(s, 1);
    float mean = s * (1.f / 128.f);
    float v = 0.f;
    for (int c2 = 0; c2 < 64; ++c2) { float d = tp[c2] - mean; v += d * d; }
    v += __shfl_xor(v, 1);
    if (jj == 0) { mu[r] = mean; rs[r] = 1.f / sqrtf(v * (1.f / 128.f) + 1e-5f); }
  }
  __syncthreads();
  for (int c = tid; c < 4096; c += 256) {
    int r = c >> 5, c4 = c & 31;
    int grow = m0 + r;
    if (grow >= M) continue;
    float4 t = ld4(Tf + r * 132 + c4 * 4);
    float4 gv = ld4(G + c4 * 4), bv = ld4(Bb + c4 * 4);
    float m = mu[r], ir = rs[r];
    float o0 = gv.x * (t.x - m) * ir + bv.x;
    float o1 = gv.y * (t.y - m) * ir + bv.y;
    float o2 = gv.z * (t.z - m) * ir + bv.z;
    float o3 = gv.w * (t.w - m) * ir + bv.w;
    u16x4 ub = { f2bfu(o0), f2bfu(o1), f2bfu(o2), f2bfu(o3) };
    *reinterpret_cast<u16x4*>(OutB + (size_t)grow * 128 + c4 * 4) = ub;
    if (OutF) st4(OutF + (size_t)grow * 128 + c4 * 4, make_float4(o0, o1, o2, o3));
  }
}

// ---------- fused MFMA FFN: out = LN(x + relu(x@W1+b1)@W2+b2) ----------
// 64 rows/block; W1T [256][128] then W2T [128][256] staged whole into one LDS region.
__global__ __launch_bounds__(256)
void ffn_bf_k(const ushort_t* __restrict__ Xbf, const float* __restrict__ ResF,
              const ushort_t* __restrict__ W1T, const float* __restrict__ B1,
              const ushort_t* __restrict__ W2T, const float* __restrict__ B2,
              const float* __restrict__ G, const float* __restrict__ Bb,
              ushort_t* __restrict__ OutB, float* __restrict__ OutF, int M)
{
  __shared__ __align__(16) ushort_t SM[8704 + 16896 + 34816];  // Xs | Mid | Wst
  __shared__ float mu[64], rs[64];
  ushort_t* Xs  = SM;              // [64][136]
  ushort_t* Mid = SM + 8704;       // [64][264] bf16; later [64][132] f32
  ushort_t* Wst = SM + 25600;      // [256][136] (W1T) / [128][264] (W2T)
  const int tid = threadIdx.x;
  const int m0 = blockIdx.x * 64;
  const int l = tid & 63, wv = tid >> 6, lr = l & 15, lk = l >> 4;
  const f32x4 zf = {0.f, 0.f, 0.f, 0.f};

  for (int c = tid; c < 1024; c += 256) {
    int r = c >> 4, k8 = c & 15;
    bf16x8 v = {};
    if (m0 + r < M)
      v = *reinterpret_cast<const bf16x8*>(Xbf + (size_t)(m0 + r) * 128 + k8 * 8);
    *reinterpret_cast<bf16x8*>(Xs + r * 136 + k8 * 8) = v;
  }
  for (int c = tid; c < 4096; c += 256)
    *reinterpret_cast<bf16x8*>(Wst + (c >> 4) * 136 + (c & 15) * 8) =
        *reinterpret_cast<const bf16x8*>(W1T + (size_t)c * 8);
  __syncthreads();

  // pass 1: Mid = relu(X@W1 + b1)  [64 x 256]; wave cols = wv*64
  {
    const int nb = wv * 64;
    f32x4 a1[4][4];
#pragma unroll
    for (int mi = 0; mi < 4; ++mi)
#pragma unroll
      for (int ni = 0; ni < 4; ++ni) a1[mi][ni] = zf;
#pragma unroll
    for (int kt = 0; kt < 4; ++kt) {
      bf16x8 af[4], bw[4];
#pragma unroll
      for (int i = 0; i < 4; ++i)
        af[i] = *reinterpret_cast<const bf16x8*>(Xs + (i * 16 + lr) * 136 + kt * 32 + lk * 8);
#pragma unroll
      for (int i = 0; i < 4; ++i)
        bw[i] = *reinterpret_cast<const bf16x8*>(Wst + (nb + i * 16 + lr) * 136 + kt * 32 + lk * 8);
#pragma unroll
      for (int mi = 0; mi < 4; ++mi)
#pragma unroll
        for (int ni = 0; ni < 4; ++ni)
          a1[mi][ni] = __builtin_amdgcn_mfma_f32_16x16x32_bf16(af[mi], bw[ni], a1[mi][ni], 0, 0, 0);
    }
#pragma unroll
    for (int mi = 0; mi < 4; ++mi)
#pragma unroll
      for (int rr = 0; rr < 4; ++rr) {
        int row = mi * 16 + lk * 4 + rr;
#pragma unroll
        for (int ni = 0; ni < 4; ++ni) {
          int col = nb + ni * 16 + lr;
          Mid[row * 264 + col] = f2bfu(fmaxf(a1[mi][ni][rr] + B1[col], 0.f));
        }
      }
  }
  __syncthreads();
  for (int c = tid; c < 4096; c += 256)
    *reinterpret_cast<bf16x8*>(Wst + (c >> 5) * 264 + (c & 31) * 8) =
        *reinterpret_cast<const bf16x8*>(W2T + (size_t)c * 8);
  __syncthreads();

  // pass 2: acc2 = Mid@W2  [64 x 128]; wave cols = wv*32; K=256
  f32x4 a2[4][2];
#pragma unroll
  for (int mi = 0; mi < 4; ++mi)
#pragma unroll
    for (int ni = 0; ni < 2; ++ni) a2[mi][ni] = zf;
  {
    const int nb2 = wv * 32;
#pragma unroll
    for (int kt = 0; kt < 8; ++kt) {
      bf16x8 af[4], bw[2];
#pragma unroll
      for (int i = 0; i < 4; ++i)
        af[i] = *reinterpret_cast<const bf16x8*>(Mid + (i * 16 + lr) * 264 + kt * 32 + lk * 8);
#pragma unroll
      for (int i = 0; i < 2; ++i)
        bw[i] = *reinterpret_cast<const bf16x8*>(Wst + (nb2 + i * 16 + lr) * 264 + kt * 32 + lk * 8);
#pragma unroll
      for (int mi = 0; mi < 4; ++mi)
#pragma unroll
        for (int ni = 0; ni < 2; ++ni)
          a2[mi][ni] = __builtin_amdgcn_mfma_f32_16x16x32_bf16(af[mi], bw[ni], a2[mi][ni], 0, 0, 0);
    }
  }
  __syncthreads();   // all Mid reads done
  float* Tf = reinterpret_cast<float*>(Mid);   // [64][132]
  {
    const int nb2 = wv * 32;
#pragma unroll
    for (int mi = 0; mi < 4; ++mi)
#pragma unroll
      for (int rr = 0; rr < 4; ++rr) {
        int row = mi * 16 + lk * 4 + rr;
        int grow = m0 + row;
#pragma unroll
        for (int ni = 0; ni < 2; ++ni) {
          int col = nb2 + ni * 16 + lr;
          float t = a2[mi][ni][rr] + B2[col];
          if (ResF) { if (grow < M) t += ResF[(size_t)grow * 128 + col]; }
          else      t += bf2f(Xs[row * 136 + col]);
          Tf[row * 132 + col] = t;
        }
      }
  }
  __syncthreads();
  {
    int r = tid >> 2, jj = tid & 3;
    const float* tp = Tf + r * 132 + jj * 32;
    float s = 0.f;
    for (int c2 = 0; c2 < 32; ++c2) s += tp[c2];
    s += __shfl_xor(s, 1); s += __shfl_xor(s, 2);
    float mean = s * (1.f / 128.f);
    float v = 0.f;
    for (int c2 = 0; c2 < 32; ++c2) { float d = tp[c2] - mean; v += d * d; }
    v += __shfl_xor(v, 1); v += __shfl_xor(v, 2);
    if (jj == 0) { mu[r] = mean; rs[r] = 1.f / sqrtf(v * (1.f / 128.f) + 1e-5f); }
  }
  __syncthreads();
  for (int c = tid; c < 2048; c += 256) {
    int r = c >> 5, c4 = c & 31;
    int grow = m0 + r;
    if (grow >= M) continue;
    float4 t = ld4(Tf + r * 132 + c4 * 4);
    float4 gv = ld4(G + c4 * 4), bv = ld4(Bb + c4 * 4);
    float m = mu[r], ir = rs[r];
    float o0 = gv.x * (t.x - m) * ir + bv.x;
    float o1 = gv.y * (t.y - m) * ir + bv.y;
    float o2 = gv.z * (t.z - m) * ir + bv.z;
    float o3 = gv.w * (t.w - m) * ir + bv.w;
    u16x4 ub = { f2bfu(o0), f2bfu(o1), f2bfu(o2), f2bfu(o3) };
    *reinterpret_cast<u16x4*>(OutB + (size_t)grow * 128 + c4 * 4) = ub;
    if (OutF) st4(OutF + (size_t)grow * 128 + c4 * 4, make_float4(o0, o1, o2, o3));
  }
}

// ---------- per-edge attention (bf16 in, deterministic fixed-point sums) ----------
__global__ __launch_bounds__(256)
void edge_bf_k(const ushort_t* __restrict__ Q, const ushort_t* __restrict__ K,
               const ushort_t* __restrict__ V, ushort_t* __restrict__ PE,
               const int* __restrict__ src, const int* __restrict__ dst,
               long long* __restrict__ wV, long long* __restrict__ z)
{
  int t = blockIdx.x * 256 + threadIdx.x;
  int e = t >> 4;
  if (e >= NE) return;
  int j = t & 15;
  int s = src[e], d = dst[e];
  u16x8 kv = *reinterpret_cast<const u16x8*>(K + (size_t)s * 128 + j * 8);
  u16x8 qv = *reinterpret_cast<const u16x8*>(Q + (size_t)d * 128 + j * 8);
  u16x8 pv = *reinterpret_cast<const u16x8*>(PE + (size_t)e * 128 + j * 8);
  u16x8 vv = *reinterpret_cast<const u16x8*>(V + (size_t)s * 128 + j * 8);
  float hsum = 0.f;
  u16x8 ob;
#pragma unroll
  for (int i = 0; i < 8; ++i) {
    float x = bf2f(kv[i]) * bf2f(qv[i]) * 0.25f * bf2f(pv[i]);
    hsum += x; ob[i] = f2bfu(x);
  }
  *reinterpret_cast<u16x8*>(PE + (size_t)e * 128 + j * 8) = ob;
  hsum += __shfl_xor(hsum, 1);   // pair j^1 shares the 16-ch head
  float w = expf(fminf(fmaxf(hsum, -5.f), 5.f));
  long long* wp = wV + (size_t)d * 128 + j * 8;
#pragma unroll
  for (int i = 0; i < 8; ++i) atomAddFx(wp + i, bf2f(vv[i]) * w);
  if ((j & 1) == 0) atomAddFx(z + (size_t)d * 8 + (j >> 1), w);
}

// ---------- h_att = wV / (z + 1e-6) -> bf16 ----------
__global__ __launch_bounds__(256)
void hatt_k(const long long* __restrict__ wV, const long long* __restrict__ z,
            ushort_t* __restrict__ outb)
{
  int t = blockIdx.x * 256 + threadIdx.x;
  if (t >= NN * 16) return;
  int n = t >> 4, j = t & 15;
  float zz = fx2f(z[(size_t)n * 8 + (j >> 1)]) + 1e-6f;
  const long long* wp = wV + (size_t)n * 128 + j * 8;
  u16x8 ob;
#pragma unroll
  for (int i = 0; i < 8; ++i) ob[i] = f2bfu(fx2f(wp[i]) / zz);
  *reinterpret_cast<u16x8*>(outb + (size_t)n * 128 + j * 8) = ob;
}

// ---------- per-graph mean over 1000 nodes ----------
__global__ __launch_bounds__(256)
void graphmean_k(const float* __restrict__ h, float* __restrict__ hg)
{
  __shared__ float red[256];
  int g = blockIdx.x, tid = threadIdx.x;
  int c = tid & 127, half = tid >> 7;
  float s = 0.f;
  for (int r = half; r < 1000; r += 2) s += h[(size_t)(g * 1000 + r) * 128 + c];
  red[tid] = s;
  __syncthreads();
  if (half == 0) hg[g * 128 + c] = (red[c] + red[c + 128]) / 1000.0f;
}

// ---------- readout MLP: 128 -> 64 -> 32 -> 1 ----------
__global__ __launch_bounds__(256)
void readout_k(const float* __restrict__ hg,
               const float* __restrict__ w0, const float* __restrict__ b0,
               const float* __restrict__ w1, const float* __restrict__ b1,
               const float* __restrict__ w2, const float* __restrict__ b2,
               float* __restrict__ out)
{
  __shared__ float hs[25 * 128];
  __shared__ float t0[25 * 64];
  __shared__ float t1[25 * 32];
  int tid = threadIdx.x;
  for (int i = tid; i < 25 * 128; i += 256) hs[i] = hg[i];
  __syncthreads();
  for (int i = tid; i < 25 * 64; i += 256) {
    int r = i >> 6, c = i & 63;
    float a = b0[c];
    for (int k = 0; k < 128; k++) a += hs[r * 128 + k] * w0[k * 64 + c];
    t0[i] = fmaxf(a, 0.f);
  }
  __syncthreads();
  for (int i = tid; i < 25 * 32; i += 256) {
    int r = i >> 5, c = i & 31;
    float a = b1[c];
    for (int k = 0; k < 64; k++) a += t0[r * 64 + k] * w1[k * 32 + c];
    t1[i] = fmaxf(a, 0.f);
  }
  __syncthreads();
  if (tid < 25) {
    float a = b2[0];
    for (int k = 0; k < 32; k++) a += t1[tid * 32 + k] * w2[k];
    out[tid] = a;
  }
}

extern "C" void kernel_launch(void* const* d_in, const int* in_sizes, int n_in,
                              void* d_out, int out_size, void* d_ws, size_t ws_size,
                              hipStream_t stream)
{
  const float* emb_h  = (const float*)d_in[0];
  const float* emb_e  = (const float*)d_in[1];
  const float* w_qkve = (const float*)d_in[2];
  const float* o_w    = (const float*)d_in[3];
  const float* o_b    = (const float*)d_in[4];
  const float* ln_s   = (const float*)d_in[5];
  const float* ln_b   = (const float*)d_in[6];
  const float* ffn_w1 = (const float*)d_in[7];
  const float* ffn_b1 = (const float*)d_in[8];
  const float* ffn_w2 = (const float*)d_in[9];
  const float* ffn_b2 = (const float*)d_in[10];
  const float* mlp_w0 = (const float*)d_in[11];
  const float* mlp_b0 = (const float*)d_in[12];
  const float* mlp_w1 = (const float*)d_in[13];
  const float* mlp_b1 = (const float*)d_in[14];
  const float* mlp_w2 = (const float*)d_in[15];
  const float* mlp_b2 = (const float*)d_in[16];
  const int* tokens = (const int*)d_in[17];
  const int* etype  = (const int*)d_in[18];
  const int* src    = (const int*)d_in[19];
  const int* dst    = (const int*)d_in[20];

  // ---- workspace: 227.4 MB total (<= 236.8 MB known-good) ----
  char* ws = (char*)d_ws;
  size_t off = 0;
  auto alloc = [&](size_t bytes) { char* p = ws + off; off += bytes; return p; };
  long long* wVll  = (long long*)alloc((size_t)NN * 128 * 8);   // 25.6 MB
  long long* zll   = (long long*)alloc((size_t)NN * 8 * 8);     // 1.6 MB
  float*     h     = (float*)alloc((size_t)NN * 128 * 4);       // 12.8 MB
  float*     hg    = (float*)alloc(25 * 128 * 4);
  ushort_t*  h_bf  = (ushort_t*)alloc((size_t)NN * 128 * 2);    // 6.4 MB
  ushort_t*  ha_bf = (ushort_t*)alloc((size_t)NN * 128 * 2);
  ushort_t*  Qb    = (ushort_t*)alloc((size_t)NN * 128 * 2);
  ushort_t*  Kb    = (ushort_t*)alloc((size_t)NN * 128 * 2);
  ushort_t*  Vb    = (ushort_t*)alloc((size_t)NN * 128 * 2);
  ushort_t*  e_bf  = (ushort_t*)alloc((size_t)NE * 128 * 2);    // 76.8 MB
  ushort_t*  sc_bf = (ushort_t*)alloc((size_t)NE * 128 * 2);    // 76.8 MB
  ushort_t*  wt    = (ushort_t*)alloc(917504 * 2);              // 1.84 MB

  // packed transposed bf16 weights
  ushort_t* qkveT = wt;            // 16 mats [128][128]
  ushort_t* owT   = wt + 262144;   // 8 mats  [128][128]
  ushort_t* w1T   = wt + 393216;   // 8 mats  [256][128]
  ushort_t* w2T   = wt + 655360;   // 8 mats  [128][256]
  wconv_k<<<1024, 256, 0, stream>>>(w_qkve, qkveT, 128, 128, 262144);
  wconv_k<<<512,  256, 0, stream>>>(o_w,    owT,   128, 128, 131072);
  wconv_k<<<1024, 256, 0, stream>>>(ffn_w1, w1T,   128, 256, 262144);
  wconv_k<<<1024, 256, 0, stream>>>(ffn_w2, w2T,   256, 128, 262144);

  gather_h_k<<<3125, 256, 0, stream>>>(emb_h, tokens, h, h_bf);
  gather_e_k<<<37500, 256, 0, stream>>>(emb_e, etype, e_bf);

  const int GN = (NN + 127) / 128;   // 196
  const int GE = (NE + 127) / 128;   // 2344
  const int FN = (NN + 63) / 64;     // 391
  const int FE = (NE + 63) / 64;     // 4688

  for (int l = 0; l < 4; ++l) {
    const ushort_t* wqT  = qkveT + ((size_t)l * 4 + 0) * 16384;
    const ushort_t* wkT  = qkveT + ((size_t)l * 4 + 1) * 16384;
    const ushort_t* wvT  = qkveT + ((size_t)l * 4 + 2) * 16384;
    const ushort_t* weT  = qkveT + ((size_t)l * 4 + 3) * 16384;
    const ushort_t* ow0T = owT + ((size_t)l * 2 + 0) * 16384;
    const ushort_t* ow1T = owT + ((size_t)l * 2 + 1) * 16384;
    const ushort_t* w1hT = w1T + ((size_t)l * 2 + 0) * 32768;
    const ushort_t* w1eT = w1T + ((size_t)l * 2 + 1) * 32768;
    const ushort_t* w2hT = w2T + ((size_t)l * 2 + 0) * 32768;
    const ushort_t* w2eT = w2T + ((size_t)l * 2 + 1) * 32768;
    const float* ob0 = o_b + ((size_t)l * 2 + 0) * 128;
    const float* ob1 = o_b + ((size_t)l * 2 + 1) * 128;
    const float* ls0 = ln_s + ((size_t)l * 4 + 0) * 128;
    const float* ls1 = ln_s + ((size_t)l * 4 + 1) * 128;
    const float* ls2 = ln_s + ((size_t)l * 4 + 2) * 128;
    const float* ls3 = ln_s + ((size_t)l * 4 + 3) * 128;
    const float* lb0 = ln_b + ((size_t)l * 4 + 0) * 128;
    const float* lb1 = ln_b + ((size_t)l * 4 + 1) * 128;
    const float* lb2 = ln_b + ((size_t)l * 4 + 2) * 128;
    const float* lb3 = ln_b + ((size_t)l * 4 + 3) * 128;
    const float* fb1h = ffn_b1 + ((size_t)l * 2 + 0) * 256;
    const float* fb1e = ffn_b1 + ((size_t)l * 2 + 1) * 256;
    const float* fb2h = ffn_b2 + ((size_t)l * 2 + 0) * 128;
    const float* fb2e = ffn_b2 + ((size_t)l * 2 + 1) * 128;

    gemm_bf_k<<<GN, 256, 0, stream>>>(h_bf, wqT, nullptr, nullptr, nullptr,
                                      nullptr, nullptr, Qb, nullptr, NN);
    gemm_bf_k<<<GN, 256, 0, stream>>>(h_bf, wkT, nullptr, nullptr, nullptr,
                                      nullptr, nullptr, Kb, nullptr, NN);
    gemm_bf_k<<<GN, 256, 0, stream>>>(h_bf, wvT, nullptr, nullptr, nullptr,
                                      nullptr, nullptr, Vb, nullptr, NN);
    gemm_bf_k<<<GE, 256, 0, stream>>>(e_bf, weT, nullptr, nullptr, nullptr,
                                      nullptr, nullptr, sc_bf, nullptr, NE);

    hipMemsetAsync(wVll, 0, (size_t)NN * 128 * 8, stream);
    hipMemsetAsync(zll, 0, (size_t)NN * 8 * 8, stream);

    edge_bf_k<<<18750, 256, 0, stream>>>(Qb, Kb, Vb, sc_bf, src, dst, wVll, zll);
    hatt_k<<<1563, 256, 0, stream>>>(wVll, zll, ha_bf);

    // h = LN(h + h_att@O_h + b); dual write fp32+bf16 (in place)
    gemm_bf_k<<<GN, 256, 0, stream>>>(ha_bf, ow0T, ob0, h, nullptr,
                                      ls0, lb0, h_bf, h, NN);
    // e = LN(e + e_att@O_e + b); bf16 (in place)
    gemm_bf_k<<<GE, 256, 0, stream>>>(sc_bf, ow1T, ob1, nullptr, e_bf,
                                      ls1, lb1, e_bf, nullptr, NE);

    ffn_bf_k<<<FN, 256, 0, stream>>>(h_bf, h, w1hT, fb1h, w2hT, fb2h,
                                     ls2, lb2, h_bf, h, NN);
    ffn_bf_k<<<FE, 256, 0, stream>>>(e_bf, nullptr, w1eT, fb1e, w2eT, fb2e,
                                     ls3, lb3, e_bf, nullptr, NE);
  }

  graphmean_k<<<25, 256, 0, stream>>>(h, hg);
  readout_k<<<1, 256, 0, stream>>>(hg, mlp_w0, mlp_b0, mlp_w1, mlp_b1, mlp_w2, mlp_b2,
                                   (float*)d_out);
}

// Round 5
// 2719.112 us; speedup vs baseline: 5.4612x; 3.5751x over previous
//
#include <hip/hip_runtime.h>
#include <cstdint>

#define NN 25000
#define NE 300000

typedef unsigned short ushort_t;
typedef __attribute__((ext_vector_type(8))) short bf16x8;
typedef __attribute__((ext_vector_type(4))) float f32x4;
typedef __attribute__((ext_vector_type(4))) unsigned short u16x4;
typedef __attribute__((ext_vector_type(8))) unsigned short u16x8;

__device__ __forceinline__ float4 ld4(const float* p){ return *reinterpret_cast<const float4*>(p); }
__device__ __forceinline__ void st4(float* p, const float4& v){ *reinterpret_cast<float4*>(p) = v; }
__device__ __forceinline__ float bf2f(ushort_t u){ return __uint_as_float((unsigned)u << 16); }
__device__ __forceinline__ ushort_t f2bfu(float f){
  unsigned x = __float_as_uint(f);
  return (ushort_t)((x + 0x7fffu + ((x >> 16) & 1u)) >> 16);   // RNE
}

// fixed-point (2^32): order-independent integer accumulation -> deterministic
#define FXS 4294967296.0
#define FXI 2.3283064365386963e-10
__device__ __forceinline__ long long f2fx(float v) {
  return (long long)llrint((double)v * FXS);
}
__device__ __forceinline__ float fx2f(long long q) { return (float)((double)q * FXI); }

// ---------- weight convert+transpose: dst[mat][n][k] = bf16(src[mat][k][n]) ----------
__global__ __launch_bounds__(256)
void wconv_k(const float* __restrict__ src, ushort_t* __restrict__ dst,
             int K, int N, int total)
{
  int i = blockIdx.x * 256 + threadIdx.x;
  if (i >= total) return;
  int kn = K * N;
  int mat = i / kn, r = i - mat * kn;
  int n = r / K, k = r - n * K;
  dst[i] = f2bfu(src[(size_t)mat * kn + (size_t)k * N + n]);
}

// ---------- gathers ----------
__global__ __launch_bounds__(256)
void gather_h_k(const float* __restrict__ tab, const int* __restrict__ idx,
                float* __restrict__ hf, ushort_t* __restrict__ hb)
{
  int t = blockIdx.x * 256 + threadIdx.x;
  if (t >= NN * 32) return;
  int i = t >> 5, c4 = t & 31;
  float4 v = ld4(tab + (size_t)idx[i] * 128 + c4 * 4);
  st4(hf + (size_t)i * 128 + c4 * 4, v);
  u16x4 b = { f2bfu(v.x), f2bfu(v.y), f2bfu(v.z), f2bfu(v.w) };
  *reinterpret_cast<u16x4*>(hb + (size_t)i * 128 + c4 * 4) = b;
}

__global__ __launch_bounds__(256)
void gather_e_k(const float* __restrict__ tab, const int* __restrict__ idx,
                ushort_t* __restrict__ eb)
{
  int t = blockIdx.x * 256 + threadIdx.x;
  if (t >= NE * 32) return;
  int i = t >> 5, c4 = t & 31;
  float4 v = ld4(tab + (size_t)idx[i] * 128 + c4 * 4);
  u16x4 b = { f2bfu(v.x), f2bfu(v.y), f2bfu(v.z), f2bfu(v.w) };
  *reinterpret_cast<u16x4*>(eb + (size_t)i * 128 + c4 * 4) = b;
}

// ---------- CSR build (per call; graph shared by all 4 layers) ----------
__global__ __launch_bounds__(256)
void count_k(const int* __restrict__ dst, int* __restrict__ counts)
{
  int e = blockIdx.x * 256 + threadIdx.x;
  if (e < NE) atomicAdd(&counts[dst[e]], 1);
}

__global__ __launch_bounds__(1024)
void scan_k(const int* __restrict__ counts, int* __restrict__ start,
            int* __restrict__ cursor)
{
  __shared__ int part[1024];
  const int t = threadIdx.x;
  const int base = t * 25;                    // 1024*25 = 25600 >= NN
  int loc[25];
  int s = 0;
#pragma unroll
  for (int i = 0; i < 25; ++i) {
    int n = base + i;
    int c = (n < NN) ? counts[n] : 0;
    loc[i] = s; s += c;
  }
  part[t] = s;
  __syncthreads();
  for (int off = 1; off < 1024; off <<= 1) {
    int v = (t >= off) ? part[t - off] : 0;
    __syncthreads();
    part[t] += v;
    __syncthreads();
  }
  int excl = (t == 0) ? 0 : part[t - 1];
#pragma unroll
  for (int i = 0; i < 25; ++i) {
    int n = base + i;
    if (n < NN) { int v = excl + loc[i]; start[n] = v; cursor[n] = v; }
  }
  if (t == 0) start[NN] = NE;
}

__global__ __launch_bounds__(256)
void scatter_k(const int* __restrict__ src, const int* __restrict__ dst,
               int* __restrict__ cursor, int2* __restrict__ csr_es)
{
  int e = blockIdx.x * 256 + threadIdx.x;
  if (e >= NE) return;
  int pos = atomicAdd(&cursor[dst[e]], 1);    // order nondet; reduce is order-indep
  csr_es[pos] = make_int2(e, src[e]);
}

// ---------- MFMA GEMM: [M,128]@[128,128]; optional bias+resid+LN epilogue ----------
__global__ __launch_bounds__(256)
void gemm_bf_k(const ushort_t* __restrict__ Abf, const ushort_t* __restrict__ WT,
               const float* __restrict__ Bias,
               const float* __restrict__ ResF, const ushort_t* __restrict__ ResB,
               const float* __restrict__ G, const float* __restrict__ Bb,
               ushort_t* __restrict__ OutB, float* __restrict__ OutF, int M)
{
  __shared__ __align__(16) ushort_t SM[2 * 128 * 136];
  __shared__ float mu[128], rs[128];
  ushort_t* Xs = SM;
  ushort_t* Ws = SM + 128 * 136;
  const int tid = threadIdx.x;
  const int m0 = blockIdx.x * 128;

  for (int c = tid; c < 2048; c += 256) {
    int r = c >> 4, k8 = c & 15;
    bf16x8 v = {};
    if (m0 + r < M)
      v = *reinterpret_cast<const bf16x8*>(Abf + (size_t)(m0 + r) * 128 + k8 * 8);
    *reinterpret_cast<bf16x8*>(Xs + r * 136 + k8 * 8) = v;
  }
  for (int c = tid; c < 2048; c += 256)
    *reinterpret_cast<bf16x8*>(Ws + (c >> 4) * 136 + (c & 15) * 8) =
        *reinterpret_cast<const bf16x8*>(WT + (size_t)c * 8);
  __syncthreads();

  const int l = tid & 63, wv = tid >> 6;
  const int lr = l & 15, lk = l >> 4;
  const int mb = (wv & 1) * 64, nb = (wv >> 1) * 64;
  f32x4 acc[4][4];
  const f32x4 zf = {0.f, 0.f, 0.f, 0.f};
#pragma unroll
  for (int mi = 0; mi < 4; ++mi)
#pragma unroll
    for (int ni = 0; ni < 4; ++ni) acc[mi][ni] = zf;

#pragma unroll
  for (int kt = 0; kt < 4; ++kt) {
    bf16x8 af[4], bw[4];
#pragma unroll
    for (int i = 0; i < 4; ++i)
      af[i] = *reinterpret_cast<const bf16x8*>(Xs + (mb + i * 16 + lr) * 136 + kt * 32 + lk * 8);
#pragma unroll
    for (int i = 0; i < 4; ++i)
      bw[i] = *reinterpret_cast<const bf16x8*>(Ws + (nb + i * 16 + lr) * 136 + kt * 32 + lk * 8);
#pragma unroll
    for (int mi = 0; mi < 4; ++mi)
#pragma unroll
      for (int ni = 0; ni < 4; ++ni)
        acc[mi][ni] = __builtin_amdgcn_mfma_f32_16x16x32_bf16(af[mi], bw[ni], acc[mi][ni], 0, 0, 0);
  }

  if (G == nullptr) {   // plain GEMM -> bf16 out
#pragma unroll
    for (int mi = 0; mi < 4; ++mi)
#pragma unroll
      for (int rr = 0; rr < 4; ++rr) {
        int row = m0 + mb + mi * 16 + lk * 4 + rr;
        if (row < M) {
#pragma unroll
          for (int ni = 0; ni < 4; ++ni)
            OutB[(size_t)row * 128 + nb + ni * 16 + lr] = f2bfu(acc[mi][ni][rr]);
        }
      }
    return;
  }

  // epilogue: T = acc + bias + resid; LN
  __syncthreads();
  float* Tf = reinterpret_cast<float*>(SM);   // [128][132]
#pragma unroll
  for (int mi = 0; mi < 4; ++mi)
#pragma unroll
    for (int rr = 0; rr < 4; ++rr) {
      int row = mb + mi * 16 + lk * 4 + rr;
      int grow = m0 + row;
#pragma unroll
      for (int ni = 0; ni < 4; ++ni) {
        int col = nb + ni * 16 + lr;
        float t = acc[mi][ni][rr] + Bias[col];
        if (grow < M)
          t += ResF ? ResF[(size_t)grow * 128 + col] : bf2f(ResB[(size_t)grow * 128 + col]);
        Tf[row * 132 + col] = t;
      }
    }
  __syncthreads();
  {
    int r = tid >> 1, jj = tid & 1;
    const float* tp = Tf + r * 132 + jj * 64;
    float s = 0.f;
    for (int c2 = 0; c2 < 64; ++c2) s += tp[c2];
    s += __shfl_xor(s, 1);
    float mean = s * (1.f / 128.f);
    float v = 0.f;
    for (int c2 = 0; c2 < 64; ++c2) { float d = tp[c2] - mean; v += d * d; }
    v += __shfl_xor(v, 1);
    if (jj == 0) { mu[r] = mean; rs[r] = 1.f / sqrtf(v * (1.f / 128.f) + 1e-5f); }
  }
  __syncthreads();
  for (int c = tid; c < 4096; c += 256) {
    int r = c >> 5, c4 = c & 31;
    int grow = m0 + r;
    if (grow >= M) continue;
    float4 t = ld4(Tf + r * 132 + c4 * 4);
    float4 gv = ld4(G + c4 * 4), bv = ld4(Bb + c4 * 4);
    float m = mu[r], ir = rs[r];
    float o0 = gv.x * (t.x - m) * ir + bv.x;
    float o1 = gv.y * (t.y - m) * ir + bv.y;
    float o2 = gv.z * (t.z - m) * ir + bv.z;
    float o3 = gv.w * (t.w - m) * ir + bv.w;
    u16x4 ub = { f2bfu(o0), f2bfu(o1), f2bfu(o2), f2bfu(o3) };
    *reinterpret_cast<u16x4*>(OutB + (size_t)grow * 128 + c4 * 4) = ub;
    if (OutF) st4(OutF + (size_t)grow * 128 + c4 * 4, make_float4(o0, o1, o2, o3));
  }
}

// ---------- fused MFMA FFN: out = LN(x + relu(x@W1+b1)@W2+b2) ----------
__global__ __launch_bounds__(256)
void ffn_bf_k(const ushort_t* __restrict__ Xbf, const float* __restrict__ ResF,
              const ushort_t* __restrict__ W1T, const float* __restrict__ B1,
              const ushort_t* __restrict__ W2T, const float* __restrict__ B2,
              const float* __restrict__ G, const float* __restrict__ Bb,
              ushort_t* __restrict__ OutB, float* __restrict__ OutF, int M)
{
  __shared__ __align__(16) ushort_t SM[8704 + 16896 + 34816];  // Xs | Mid | Wst
  __shared__ float mu[64], rs[64];
  ushort_t* Xs  = SM;              // [64][136]
  ushort_t* Mid = SM + 8704;       // [64][264] bf16; later [64][132] f32
  ushort_t* Wst = SM + 25600;      // [256][136] (W1T) / [128][264] (W2T)
  const int tid = threadIdx.x;
  const int m0 = blockIdx.x * 64;
  const int l = tid & 63, wv = tid >> 6, lr = l & 15, lk = l >> 4;
  const f32x4 zf = {0.f, 0.f, 0.f, 0.f};

  for (int c = tid; c < 1024; c += 256) {
    int r = c >> 4, k8 = c & 15;
    bf16x8 v = {};
    if (m0 + r < M)
      v = *reinterpret_cast<const bf16x8*>(Xbf + (size_t)(m0 + r) * 128 + k8 * 8);
    *reinterpret_cast<bf16x8*>(Xs + r * 136 + k8 * 8) = v;
  }
  for (int c = tid; c < 4096; c += 256)
    *reinterpret_cast<bf16x8*>(Wst + (c >> 4) * 136 + (c & 15) * 8) =
        *reinterpret_cast<const bf16x8*>(W1T + (size_t)c * 8);
  __syncthreads();

  // pass 1: Mid = relu(X@W1 + b1)  [64 x 256]; wave cols = wv*64
  {
    const int nb = wv * 64;
    f32x4 a1[4][4];
#pragma unroll
    for (int mi = 0; mi < 4; ++mi)
#pragma unroll
      for (int ni = 0; ni < 4; ++ni) a1[mi][ni] = zf;
#pragma unroll
    for (int kt = 0; kt < 4; ++kt) {
      bf16x8 af[4], bw[4];
#pragma unroll
      for (int i = 0; i < 4; ++i)
        af[i] = *reinterpret_cast<const bf16x8*>(Xs + (i * 16 + lr) * 136 + kt * 32 + lk * 8);
#pragma unroll
      for (int i = 0; i < 4; ++i)
        bw[i] = *reinterpret_cast<const bf16x8*>(Wst + (nb + i * 16 + lr) * 136 + kt * 32 + lk * 8);
#pragma unroll
      for (int mi = 0; mi < 4; ++mi)
#pragma unroll
        for (int ni = 0; ni < 4; ++ni)
          a1[mi][ni] = __builtin_amdgcn_mfma_f32_16x16x32_bf16(af[mi], bw[ni], a1[mi][ni], 0, 0, 0);
    }
#pragma unroll
    for (int mi = 0; mi < 4; ++mi)
#pragma unroll
      for (int rr = 0; rr < 4; ++rr) {
        int row = mi * 16 + lk * 4 + rr;
#pragma unroll
        for (int ni = 0; ni < 4; ++ni) {
          int col = nb + ni * 16 + lr;
          Mid[row * 264 + col] = f2bfu(fmaxf(a1[mi][ni][rr] + B1[col], 0.f));
        }
      }
  }
  __syncthreads();
  for (int c = tid; c < 4096; c += 256)
    *reinterpret_cast<bf16x8*>(Wst + (c >> 5) * 264 + (c & 31) * 8) =
        *reinterpret_cast<const bf16x8*>(W2T + (size_t)c * 8);
  __syncthreads();

  // pass 2: acc2 = Mid@W2  [64 x 128]; wave cols = wv*32; K=256
  f32x4 a2[4][2];
#pragma unroll
  for (int mi = 0; mi < 4; ++mi)
#pragma unroll
    for (int ni = 0; ni < 2; ++ni) a2[mi][ni] = zf;
  {
    const int nb2 = wv * 32;
#pragma unroll
    for (int kt = 0; kt < 8; ++kt) {
      bf16x8 af[4], bw[2];
#pragma unroll
      for (int i = 0; i < 4; ++i)
        af[i] = *reinterpret_cast<const bf16x8*>(Mid + (i * 16 + lr) * 264 + kt * 32 + lk * 8);
#pragma unroll
      for (int i = 0; i < 2; ++i)
        bw[i] = *reinterpret_cast<const bf16x8*>(Wst + (nb2 + i * 16 + lr) * 264 + kt * 32 + lk * 8);
#pragma unroll
      for (int mi = 0; mi < 4; ++mi)
#pragma unroll
        for (int ni = 0; ni < 2; ++ni)
          a2[mi][ni] = __builtin_amdgcn_mfma_f32_16x16x32_bf16(af[mi], bw[ni], a2[mi][ni], 0, 0, 0);
    }
  }
  __syncthreads();   // all Mid reads done
  float* Tf = reinterpret_cast<float*>(Mid);   // [64][132]
  {
    const int nb2 = wv * 32;
#pragma unroll
    for (int mi = 0; mi < 4; ++mi)
#pragma unroll
      for (int rr = 0; rr < 4; ++rr) {
        int row = mi * 16 + lk * 4 + rr;
        int grow = m0 + row;
#pragma unroll
        for (int ni = 0; ni < 2; ++ni) {
          int col = nb2 + ni * 16 + lr;
          float t = a2[mi][ni][rr] + B2[col];
          if (ResF) { if (grow < M) t += ResF[(size_t)grow * 128 + col]; }
          else      t += bf2f(Xs[row * 136 + col]);
          Tf[row * 132 + col] = t;
        }
      }
  }
  __syncthreads();
  {
    int r = tid >> 2, jj = tid & 3;
    const float* tp = Tf + r * 132 + jj * 32;
    float s = 0.f;
    for (int c2 = 0; c2 < 32; ++c2) s += tp[c2];
    s += __shfl_xor(s, 1); s += __shfl_xor(s, 2);
    float mean = s * (1.f / 128.f);
    float v = 0.f;
    for (int c2 = 0; c2 < 32; ++c2) { float d = tp[c2] - mean; v += d * d; }
    v += __shfl_xor(v, 1); v += __shfl_xor(v, 2);
    if (jj == 0) { mu[r] = mean; rs[r] = 1.f / sqrtf(v * (1.f / 128.f) + 1e-5f); }
  }
  __syncthreads();
  for (int c = tid; c < 2048; c += 256) {
    int r = c >> 5, c4 = c & 31;
    int grow = m0 + r;
    if (grow >= M) continue;
    float4 t = ld4(Tf + r * 132 + c4 * 4);
    float4 gv = ld4(G + c4 * 4), bv = ld4(Bb + c4 * 4);
    float m = mu[r], ir = rs[r];
    float o0 = gv.x * (t.x - m) * ir + bv.x;
    float o1 = gv.y * (t.y - m) * ir + bv.y;
    float o2 = gv.z * (t.z - m) * ir + bv.z;
    float o3 = gv.w * (t.w - m) * ir + bv.w;
    u16x4 ub = { f2bfu(o0), f2bfu(o1), f2bfu(o2), f2bfu(o3) };
    *reinterpret_cast<u16x4*>(OutB + (size_t)grow * 128 + c4 * 4) = ub;
    if (OutF) st4(OutF + (size_t)grow * 128 + c4 * 4, make_float4(o0, o1, o2, o3));
  }
}

// ---------- edge score: sc = K[src]*Q[dst]*0.25*pe (in place), w per head ----------
__global__ __launch_bounds__(256)
void edge_score_k(const ushort_t* __restrict__ Q, const ushort_t* __restrict__ K,
                  ushort_t* __restrict__ PE,
                  const int* __restrict__ src, const int* __restrict__ dst,
                  float* __restrict__ wbuf)
{
  int t = blockIdx.x * 256 + threadIdx.x;
  int e = t >> 4;
  if (e >= NE) return;
  int j = t & 15;
  int s = src[e], d = dst[e];
  u16x8 kv = *reinterpret_cast<const u16x8*>(K + (size_t)s * 128 + j * 8);
  u16x8 qv = *reinterpret_cast<const u16x8*>(Q + (size_t)d * 128 + j * 8);
  u16x8 pv = *reinterpret_cast<const u16x8*>(PE + (size_t)e * 128 + j * 8);
  float hsum = 0.f;
  u16x8 ob;
#pragma unroll
  for (int i = 0; i < 8; ++i) {
    float x = bf2f(kv[i]) * bf2f(qv[i]) * 0.25f * bf2f(pv[i]);
    hsum += x; ob[i] = f2bfu(x);
  }
  *reinterpret_cast<u16x8*>(PE + (size_t)e * 128 + j * 8) = ob;
  hsum += __shfl_xor(hsum, 1);               // pair shares the 16-ch head
  float w = expf(fminf(fmaxf(hsum, -5.f), 5.f));
  if ((j & 1) == 0) wbuf[(size_t)e * 8 + (j >> 1)] = w;
}

// ---------- CSR gather-reduce: h_att[n] = (sum w*V[src]) / (sum w + 1e-6) ----------
// 16 lanes per node; int64 fixed-point register accumulation (order-independent).
__global__ __launch_bounds__(256)
void reduce_k(const ushort_t* __restrict__ V, const float* __restrict__ wbuf,
              const int* __restrict__ start, const int2* __restrict__ csr_es,
              ushort_t* __restrict__ out)
{
  int t = blockIdx.x * 256 + threadIdx.x;
  int n = t >> 4;
  if (n >= NN) return;
  int j = t & 15;
  int p0 = start[n], p1 = start[n + 1];
  long long acc[8] = {};
  long long zacc = 0;
  for (int p = p0; p < p1; ++p) {
    int2 es = csr_es[p];
    float w = wbuf[(size_t)es.x * 8 + (j >> 1)];
    u16x8 vv = *reinterpret_cast<const u16x8*>(V + (size_t)es.y * 128 + j * 8);
    zacc += f2fx(w);
#pragma unroll
    for (int i = 0; i < 8; ++i) acc[i] += f2fx(bf2f(vv[i]) * w);
  }
  float zz = fx2f(zacc) + 1e-6f;
  u16x8 ob;
#pragma unroll
  for (int i = 0; i < 8; ++i) ob[i] = f2bfu(fx2f(acc[i]) / zz);
  *reinterpret_cast<u16x8*>(out + (size_t)n * 128 + j * 8) = ob;
}

// ---------- per-graph mean over 1000 nodes ----------
__global__ __launch_bounds__(256)
void graphmean_k(const float* __restrict__ h, float* __restrict__ hg)
{
  __shared__ float red[256];
  int g = blockIdx.x, tid = threadIdx.x;
  int c = tid & 127, half = tid >> 7;
  float s = 0.f;
  for (int r = half; r < 1000; r += 2) s += h[(size_t)(g * 1000 + r) * 128 + c];
  red[tid] = s;
  __syncthreads();
  if (half == 0) hg[g * 128 + c] = (red[c] + red[c + 128]) / 1000.0f;
}

// ---------- readout MLP: 128 -> 64 -> 32 -> 1 ----------
__global__ __launch_bounds__(256)
void readout_k(const float* __restrict__ hg,
               const float* __restrict__ w0, const float* __restrict__ b0,
               const float* __restrict__ w1, const float* __restrict__ b1,
               const float* __restrict__ w2, const float* __restrict__ b2,
               float* __restrict__ out)
{
  __shared__ float hs[25 * 128];
  __shared__ float t0[25 * 64];
  __shared__ float t1[25 * 32];
  int tid = threadIdx.x;
  for (int i = tid; i < 25 * 128; i += 256) hs[i] = hg[i];
  __syncthreads();
  for (int i = tid; i < 25 * 64; i += 256) {
    int r = i >> 6, c = i & 63;
    float a = b0[c];
    for (int k = 0; k < 128; k++) a += hs[r * 128 + k] * w0[k * 64 + c];
    t0[i] = fmaxf(a, 0.f);
  }
  __syncthreads();
  for (int i = tid; i < 25 * 32; i += 256) {
    int r = i >> 5, c = i & 31;
    float a = b1[c];
    for (int k = 0; k < 64; k++) a += t0[r * 64 + k] * w1[k * 32 + c];
    t1[i] = fmaxf(a, 0.f);
  }
  __syncthreads();
  if (tid < 25) {
    float a = b2[0];
    for (int k = 0; k < 32; k++) a += t1[tid * 32 + k] * w2[k];
    out[tid] = a;
  }
}

extern "C" void kernel_launch(void* const* d_in, const int* in_sizes, int n_in,
                              void* d_out, int out_size, void* d_ws, size_t ws_size,
                              hipStream_t stream)
{
  const float* emb_h  = (const float*)d_in[0];
  const float* emb_e  = (const float*)d_in[1];
  const float* w_qkve = (const float*)d_in[2];
  const float* o_w    = (const float*)d_in[3];
  const float* o_b    = (const float*)d_in[4];
  const float* ln_s   = (const float*)d_in[5];
  const float* ln_b   = (const float*)d_in[6];
  const float* ffn_w1 = (const float*)d_in[7];
  const float* ffn_b1 = (const float*)d_in[8];
  const float* ffn_w2 = (const float*)d_in[9];
  const float* ffn_b2 = (const float*)d_in[10];
  const float* mlp_w0 = (const float*)d_in[11];
  const float* mlp_b0 = (const float*)d_in[12];
  const float* mlp_w1 = (const float*)d_in[13];
  const float* mlp_b1 = (const float*)d_in[14];
  const float* mlp_w2 = (const float*)d_in[15];
  const float* mlp_b2 = (const float*)d_in[16];
  const int* tokens = (const int*)d_in[17];
  const int* etype  = (const int*)d_in[18];
  const int* src    = (const int*)d_in[19];
  const int* dst    = (const int*)d_in[20];

  // ---- workspace (~219 MB; <= 227 MB known-good) ----
  char* ws = (char*)d_ws;
  size_t off = 0;
  auto alloc = [&](size_t bytes) { char* p = ws + off; off += bytes; return p; };
  int2*      csr_es = (int2*)alloc((size_t)NE * 8);             // 2.4 MB (8B align first)
  float*     h      = (float*)alloc((size_t)NN * 128 * 4);      // 12.8 MB
  float*     hg     = (float*)alloc(25 * 128 * 4);
  float*     wbuf   = (float*)alloc((size_t)NE * 8 * 4);        // 9.6 MB
  int*       counts = (int*)alloc((size_t)NN * 4);
  int*       cursor = (int*)alloc((size_t)NN * 4);
  int*       startp = (int*)alloc((size_t)(NN + 1) * 4);
  ushort_t*  h_bf   = (ushort_t*)alloc((size_t)NN * 128 * 2);   // 6.4 MB
  ushort_t*  ha_bf  = (ushort_t*)alloc((size_t)NN * 128 * 2);
  ushort_t*  Qb     = (ushort_t*)alloc((size_t)NN * 128 * 2);
  ushort_t*  Kb     = (ushort_t*)alloc((size_t)NN * 128 * 2);
  ushort_t*  Vb     = (ushort_t*)alloc((size_t)NN * 128 * 2);
  ushort_t*  e_bf   = (ushort_t*)alloc((size_t)NE * 128 * 2);   // 76.8 MB
  ushort_t*  sc_bf  = (ushort_t*)alloc((size_t)NE * 128 * 2);   // 76.8 MB
  ushort_t*  wt     = (ushort_t*)alloc(917504 * 2);             // 1.84 MB

  // packed transposed bf16 weights
  ushort_t* qkveT = wt;            // 16 mats [128][128]
  ushort_t* owT   = wt + 262144;   // 8 mats  [128][128]
  ushort_t* w1T   = wt + 393216;   // 8 mats  [256][128]
  ushort_t* w2T   = wt + 655360;   // 8 mats  [128][256]
  wconv_k<<<1024, 256, 0, stream>>>(w_qkve, qkveT, 128, 128, 262144);
  wconv_k<<<512,  256, 0, stream>>>(o_w,    owT,   128, 128, 131072);
  wconv_k<<<1024, 256, 0, stream>>>(ffn_w1, w1T,   128, 256, 262144);
  wconv_k<<<1024, 256, 0, stream>>>(ffn_w2, w2T,   256, 128, 262144);

  gather_h_k<<<3125, 256, 0, stream>>>(emb_h, tokens, h, h_bf);
  gather_e_k<<<37500, 256, 0, stream>>>(emb_e, etype, e_bf);

  // CSR by dst (shared across layers)
  hipMemsetAsync(counts, 0, (size_t)NN * 4, stream);
  count_k<<<(NE + 255) / 256, 256, 0, stream>>>(dst, counts);
  scan_k<<<1, 1024, 0, stream>>>(counts, startp, cursor);
  scatter_k<<<(NE + 255) / 256, 256, 0, stream>>>(src, dst, cursor, csr_es);

  const int GN = (NN + 127) / 128;   // 196
  const int GE = (NE + 127) / 128;   // 2344
  const int FN = (NN + 63) / 64;     // 391
  const int FE = (NE + 63) / 64;     // 4688

  for (int l = 0; l < 4; ++l) {
    const ushort_t* wqT  = qkveT + ((size_t)l * 4 + 0) * 16384;
    const ushort_t* wkT  = qkveT + ((size_t)l * 4 + 1) * 16384;
    const ushort_t* wvT  = qkveT + ((size_t)l * 4 + 2) * 16384;
    const ushort_t* weT  = qkveT + ((size_t)l * 4 + 3) * 16384;
    const ushort_t* ow0T = owT + ((size_t)l * 2 + 0) * 16384;
    const ushort_t* ow1T = owT + ((size_t)l * 2 + 1) * 16384;
    const ushort_t* w1hT = w1T + ((size_t)l * 2 + 0) * 32768;
    const ushort_t* w1eT = w1T + ((size_t)l * 2 + 1) * 32768;
    const ushort_t* w2hT = w2T + ((size_t)l * 2 + 0) * 32768;
    const ushort_t* w2eT = w2T + ((size_t)l * 2 + 1) * 32768;
    const float* ob0 = o_b + ((size_t)l * 2 + 0) * 128;
    const float* ob1 = o_b + ((size_t)l * 2 + 1) * 128;
    const float* ls0 = ln_s + ((size_t)l * 4 + 0) * 128;
    const float* ls1 = ln_s + ((size_t)l * 4 + 1) * 128;
    const float* ls2 = ln_s + ((size_t)l * 4 + 2) * 128;
    const float* ls3 = ln_s + ((size_t)l * 4 + 3) * 128;
    const float* lb0 = ln_b + ((size_t)l * 4 + 0) * 128;
    const float* lb1 = ln_b + ((size_t)l * 4 + 1) * 128;
    const float* lb2 = ln_b + ((size_t)l * 4 + 2) * 128;
    const float* lb3 = ln_b + ((size_t)l * 4 + 3) * 128;
    const float* fb1h = ffn_b1 + ((size_t)l * 2 + 0) * 256;
    const float* fb1e = ffn_b1 + ((size_t)l * 2 + 1) * 256;
    const float* fb2h = ffn_b2 + ((size_t)l * 2 + 0) * 128;
    const float* fb2e = ffn_b2 + ((size_t)l * 2 + 1) * 128;

    gemm_bf_k<<<GN, 256, 0, stream>>>(h_bf, wqT, nullptr, nullptr, nullptr,
                                      nullptr, nullptr, Qb, nullptr, NN);
    gemm_bf_k<<<GN, 256, 0, stream>>>(h_bf, wkT, nullptr, nullptr, nullptr,
                                      nullptr, nullptr, Kb, nullptr, NN);
    gemm_bf_k<<<GN, 256, 0, stream>>>(h_bf, wvT, nullptr, nullptr, nullptr,
                                      nullptr, nullptr, Vb, nullptr, NN);
    gemm_bf_k<<<GE, 256, 0, stream>>>(e_bf, weT, nullptr, nullptr, nullptr,
                                      nullptr, nullptr, sc_bf, nullptr, NE);

    edge_score_k<<<18750, 256, 0, stream>>>(Qb, Kb, sc_bf, src, dst, wbuf);
    reduce_k<<<1563, 256, 0, stream>>>(Vb, wbuf, startp, csr_es, ha_bf);

    // h = LN(h + h_att@O_h + b); dual write fp32+bf16 (in place)
    gemm_bf_k<<<GN, 256, 0, stream>>>(ha_bf, ow0T, ob0, h, nullptr,
                                      ls0, lb0, h_bf, h, NN);
    // e = LN(e + e_att@O_e + b); bf16 (in place)
    gemm_bf_k<<<GE, 256, 0, stream>>>(sc_bf, ow1T, ob1, nullptr, e_bf,
                                      ls1, lb1, e_bf, nullptr, NE);

    ffn_bf_k<<<FN, 256, 0, stream>>>(h_bf, h, w1hT, fb1h, w2hT, fb2h,
                                     ls2, lb2, h_bf, h, NN);
    ffn_bf_k<<<FE, 256, 0, stream>>>(e_bf, nullptr, w1eT, fb1e, w2eT, fb2e,
                                     ls3, lb3, e_bf, nullptr, NE);
  }

  graphmean_k<<<25, 256, 0, stream>>>(h, hg);
  readout_k<<<1, 256, 0, stream>>>(hg, mlp_w0, mlp_b0, mlp_w1, mlp_b1, mlp_w2, mlp_b2,
                                   (float*)d_out);
}